// Round 7
// baseline (279.559 us; speedup 1.0000x reference)
//
#include <hip/hip_runtime.h>
#include <hip/hip_bf16.h>

#define D 128

typedef __attribute__((ext_vector_type(8))) short bfrag;   // 8 bf16 (4 VGPRs)
typedef __attribute__((ext_vector_type(4))) float facc;    // 4 f32 acc
typedef __attribute__((ext_vector_type(4))) unsigned int u32x4;
typedef __attribute__((ext_vector_type(2))) unsigned int u32x2;
typedef __attribute__((ext_vector_type(4))) float f32x4;

__device__ __forceinline__ facc mfma16(bfrag a, bfrag b, facc c) {
    return __builtin_amdgcn_mfma_f32_16x16x32_bf16(a, b, c, 0, 0, 0);
}
__device__ __forceinline__ unsigned int bf16_rn(float f) {
    unsigned int u = __float_as_uint(f);
    u += 0x7FFF + ((u >> 16) & 1);   // round-nearest-even
    return u >> 16;
}
__device__ __forceinline__ float bf16_f(unsigned int h) {
    return __uint_as_float(h << 16);
}
// pack f32 -> (bf16_hi << 16) | bf16_lo
__device__ __forceinline__ unsigned int packf(float v) {
    unsigned int hi = bf16_rn(v);
    unsigned int lo = bf16_rn(v - bf16_f(hi));
    return (hi << 16) | lo;
}
__device__ __forceinline__ float bf16lo(unsigned int u) {
    return __uint_as_float(u << 16);
}
__device__ __forceinline__ float bf16hi(unsigned int u) {
    return __uint_as_float(u & 0xFFFF0000u);
}

// ---------------------------------------------------------------------------
// Fused prep: [0,eblk) histogram of src; [eblk,eblk+sblk) split x -> packed;
// [eblk+sblk, +128) W1 -> frag-major split-bf16 planes.
// ---------------------------------------------------------------------------
__global__ __launch_bounds__(256) void prep_kernel(
    const int* __restrict__ src, int* __restrict__ counts, int nedges,
    const float* __restrict__ x, unsigned int* __restrict__ xp, int n4,
    const float* __restrict__ W1, unsigned short* __restrict__ Wh,
    unsigned short* __restrict__ Wl, int eblk, int sblk) {
    int b = blockIdx.x;
    if (b < eblk) {
        int e = b * 256 + threadIdx.x;
        if (e < nedges) atomicAdd(&counts[src[e]], 1);
    } else if (b < eblk + sblk) {
        int i = (b - eblk) * 256 + threadIdx.x;
        if (i < n4) {
            float4 v = ((const float4*)x)[i];
            uint4 p;
            p.x = packf(v.x);
            p.y = packf(v.y);
            p.z = packf(v.z);
            p.w = packf(v.w);
            ((uint4*)xp)[i] = p;
        }
    } else {
        int j = b - eblk - sblk;   // 0..127 output col
        int k = threadIdx.x;       // 0..255
        float w = W1[(size_t)k * D + j];
        unsigned int hi = bf16_rn(w);
        size_t o = (size_t)((k >> 3) * 128 + j) * 8 + (k & 7);
        Wh[o] = (unsigned short)hi;
        Wl[o] = (unsigned short)bf16_rn(w - bf16_f(hi));
    }
}

// ---------------------------------------------------------------------------
// Multi-block exclusive scan of counts[n] (3 passes).
// ---------------------------------------------------------------------------
#define SCHUNK 2048
__global__ __launch_bounds__(256) void scan1_kernel(
    const int* __restrict__ counts, int* __restrict__ bsum, int n) {
    __shared__ int sd[256];
    const int tid = threadIdx.x;
    const int base = blockIdx.x * SCHUNK + tid * 8;
    int s = 0;
#pragma unroll
    for (int j = 0; j < 8; ++j) {
        int idx = base + j;
        if (idx < n) s += counts[idx];
    }
    sd[tid] = s;
    __syncthreads();
    for (int d2 = 128; d2; d2 >>= 1) {
        if (tid < d2) sd[tid] += sd[tid + d2];
        __syncthreads();
    }
    if (tid == 0) bsum[blockIdx.x] = sd[0];
}
__global__ void scan2_kernel(int* __restrict__ bsum, int nb) {
    int tid = threadIdx.x;
    int v = (tid < nb) ? bsum[tid] : 0;
#pragma unroll
    for (int d2 = 1; d2 < 64; d2 <<= 1) {
        int t = __shfl_up(v, d2);
        if (tid >= d2) v += t;
    }
    if (tid < nb) bsum[tid] = v;
}
__global__ __launch_bounds__(256) void scan3_kernel(
    const int* __restrict__ counts, const int* __restrict__ bsum,
    int* __restrict__ off, int* __restrict__ cur, int n) {
    __shared__ int sd[256];
    const int tid = threadIdx.x;
    const int base = blockIdx.x * SCHUNK + tid * 8;
    int loc[8];
    int s = 0;
#pragma unroll
    for (int j = 0; j < 8; ++j) {
        int idx = base + j;
        int c = (idx < n) ? counts[idx] : 0;
        loc[j] = c;
        s += c;
    }
    sd[tid] = s;
    __syncthreads();
#pragma unroll
    for (int d2 = 1; d2 < 256; d2 <<= 1) {
        int t = (tid >= d2) ? sd[tid - d2] : 0;
        __syncthreads();
        sd[tid] += t;
        __syncthreads();
    }
    int boff = (blockIdx.x == 0) ? 0 : bsum[blockIdx.x - 1];
    int pre = boff + sd[tid] - s;
#pragma unroll
    for (int j = 0; j < 8; ++j) {
        int idx = base + j;
        if (idx < n) {
            off[idx] = pre;
            cur[idx] = pre;
            pre += loc[j];
        }
    }
    if (tid == 255 && base + 8 >= n && n <= blockIdx.x * SCHUNK + SCHUNK)
        off[n] = boff + sd[255];
}

// ---------------------------------------------------------------------------
// Fill-permute: read edge rows SEQUENTIALLY, convert to bf16, write each row
// into CSR-sorted position (random 256B full-line writes -> absorbed by
// L2/L3; sorted buffer = 154MB < 256MB L3). Half-wave per edge row.
// ---------------------------------------------------------------------------
__global__ __launch_bounds__(256) void fillp_kernel(
    const float* __restrict__ edge_attr, const int* __restrict__ src,
    int* __restrict__ cur, unsigned int* __restrict__ ebS, int nedges) {
    const int l = threadIdx.x & 63;
    const int h = l >> 5;           // half-wave
    const int c = l & 31;           // 4 cols per lane
    int e = blockIdx.x * 8 + (threadIdx.x >> 6) * 2 + h;
    if (e >= nedges) return;
    f32x4 v = __builtin_nontemporal_load(
        (const f32x4*)(edge_attr + (size_t)e * D) + c);
    int slot = 0;
    if (c == 0) slot = atomicAdd(&cur[src[e]], 1);
    slot = __shfl(slot, l & 32);    // broadcast from lane h*32
    u32x2 p;
    p.x = bf16_rn(v[0]) | (bf16_rn(v[1]) << 16);
    p.y = bf16_rn(v[2]) | (bf16_rn(v[3]) << 16);
    *((u32x2*)(ebS + (size_t)slot * 64) + c) = p;
}

// ---------------------------------------------------------------------------
// Fused gather + GEMM1. Block = 256 thr (4 waves) owns 64 nodes.
// Phase 1: each wave sums its 16 nodes' sorted bf16 edge rows (contiguous,
// L3-hot) into LDS as packed split-bf16 (padded stride 132 vs bank conflicts).
// Phase 2: h1 = SiLU([x|agg] @ W1^T + b1): K=256, k<128 from xp (global,
// packed), k>=128 from LDS agg. 3 MFMAs per 16x16x32 tile. Stats for BN.
// C/D layout (m89): col = lane&15, row = (lane>>4)*4 + reg.
// ---------------------------------------------------------------------------
__global__ __launch_bounds__(256, 2) void gemm1_fused(
    const unsigned int* __restrict__ xp, const unsigned int* __restrict__ ebS,
    const int* __restrict__ off, const unsigned short* __restrict__ Wh,
    const unsigned short* __restrict__ Wl, const float* __restrict__ bias,
    unsigned int* __restrict__ h1p, float* __restrict__ gsum,
    float* __restrict__ gsq, int M) {
    __shared__ unsigned int As[64][132];
    __shared__ float sred[2][4][128];
    const int tid = threadIdx.x;
    const int w = tid >> 6;
    const int l = tid & 63;
    const int h = l >> 5;
    const int c = l & 31;
    const int row0 = blockIdx.x * 64;

    // ---- gather phase: 16 nodes per wave ----
    for (int nd = 0; nd < 16; ++nd) {
        int node = row0 + w * 16 + nd;
        if (node >= M) break;
        int s = off[node];
        const int e = off[node + 1];
        f32x4 acc = {0.f, 0.f, 0.f, 0.f};
        int i = s;
        for (; i + 16 <= e; i += 16) {
            u32x2 q[8];
#pragma unroll
            for (int u = 0; u < 8; ++u)
                q[u] = __builtin_nontemporal_load(
                    (const u32x2*)(ebS + (size_t)(i + 2 * u + h) * 64) + c);
#pragma unroll
            for (int u = 0; u < 8; ++u) {
                acc[0] += bf16lo(q[u].x);
                acc[1] += bf16hi(q[u].x);
                acc[2] += bf16lo(q[u].y);
                acc[3] += bf16hi(q[u].y);
            }
        }
        for (; i + 2 <= e; i += 2) {
            u32x2 q = __builtin_nontemporal_load(
                (const u32x2*)(ebS + (size_t)(i + h) * 64) + c);
            acc[0] += bf16lo(q.x);
            acc[1] += bf16hi(q.x);
            acc[2] += bf16lo(q.y);
            acc[3] += bf16hi(q.y);
        }
        if (i < e && h == 0) {
            u32x2 q = __builtin_nontemporal_load(
                (const u32x2*)(ebS + (size_t)i * 64) + c);
            acc[0] += bf16lo(q.x);
            acc[1] += bf16hi(q.x);
            acc[2] += bf16lo(q.y);
            acc[3] += bf16hi(q.y);
        }
#pragma unroll
        for (int r = 0; r < 4; ++r) acc[r] += __shfl_xor(acc[r], 32);
        if (h == 0) {
            u32x4 p;
#pragma unroll
            for (int r = 0; r < 4; ++r) p[r] = packf(acc[r]);
            *(u32x4*)&As[w * 16 + nd][c * 4] = p;
        }
    }
    __syncthreads();

    // ---- GEMM phase ----
    const int lr = l & 15;
    const int lk = l >> 4;
    facc acc[8];
#pragma unroll
    for (int ct = 0; ct < 8; ++ct)
#pragma unroll
        for (int r = 0; r < 4; ++r) acc[ct][r] = 0.f;

    for (int s = 0; s < 8; ++s) {
        unsigned int ua[8];
        if (s < 4) {
            const int arow = row0 + w * 16 + lr;
            const int kk = s * 32 + lk * 8;
            u32x4 q0 = {0u, 0u, 0u, 0u}, q1 = {0u, 0u, 0u, 0u};
            if (arow < M) {
                const u32x4* p = (const u32x4*)(xp + (size_t)arow * D + kk);
                q0 = p[0];
                q1 = p[1];
            }
#pragma unroll
            for (int r = 0; r < 4; ++r) {
                ua[r] = q0[r];
                ua[4 + r] = q1[r];
            }
        } else {
            const int kk = (s - 4) * 32 + lk * 8;
            const u32x4* p = (const u32x4*)&As[w * 16 + lr][kk];
            u32x4 q0 = p[0], q1 = p[1];
#pragma unroll
            for (int r = 0; r < 4; ++r) {
                ua[r] = q0[r];
                ua[4 + r] = q1[r];
            }
        }
        u32x4 uh, ul;
#pragma unroll
        for (int r = 0; r < 4; ++r) {
            uh[r] = __builtin_amdgcn_perm(ua[2 * r + 1], ua[2 * r],
                                          0x07060302u);
            ul[r] = __builtin_amdgcn_perm(ua[2 * r + 1], ua[2 * r],
                                          0x05040100u);
        }
        bfrag ah = __builtin_bit_cast(bfrag, uh);
        bfrag al = __builtin_bit_cast(bfrag, ul);

        bfrag bh[8], bl[8];
        const int fb = (s * 4 + lk) * 128;
#pragma unroll
        for (int ct = 0; ct < 8; ++ct) {
            size_t o = (size_t)(fb + ct * 16 + lr) * 8;
            bh[ct] = *(const bfrag*)(Wh + o);
            bl[ct] = *(const bfrag*)(Wl + o);
        }
#pragma unroll
        for (int ct = 0; ct < 8; ++ct) acc[ct] = mfma16(ah, bh[ct], acc[ct]);
#pragma unroll
        for (int ct = 0; ct < 8; ++ct) acc[ct] = mfma16(ah, bl[ct], acc[ct]);
#pragma unroll
        for (int ct = 0; ct < 8; ++ct) acc[ct] = mfma16(al, bh[ct], acc[ct]);
    }

    // epilogue: bias, SiLU, packed store, stats
#pragma unroll
    for (int ct = 0; ct < 8; ++ct) {
        const int col = ct * 16 + lr;
        const float bj = bias[col];
        float s = 0.f, q = 0.f;
        const int base = row0 + w * 16 + lk * 4;
#pragma unroll
        for (int r = 0; r < 4; ++r) {
            int crow = base + r;
            if (crow < M) {
                float v = acc[ct][r] + bj;
                v = v / (1.0f + __expf(-v));
                h1p[(size_t)crow * D + col] = packf(v);
                s += v;
                q += v * v;
            }
        }
        s += __shfl_xor(s, 16);
        s += __shfl_xor(s, 32);
        q += __shfl_xor(q, 16);
        q += __shfl_xor(q, 32);
        if (lk == 0) {
            sred[0][w][col] = s;
            sred[1][w][col] = q;
        }
    }
    __syncthreads();
    if (tid < 128) {
        float v = sred[0][0][tid] + sred[0][1][tid] + sred[0][2][tid] +
                  sred[0][3][tid];
        unsafeAtomicAdd(&gsum[tid], v);
    } else {
        int cc = tid - 128;
        float v = sred[1][0][cc] + sred[1][1][cc] + sred[1][2][cc] +
                  sred[1][3][cc];
        unsafeAtomicAdd(&gsq[cc], v);
    }
}

// ---------------------------------------------------------------------------
// Fold BN (batch stats) into next layer's W; frag-major split planes + bias.
// ---------------------------------------------------------------------------
__global__ void fold_kernel(const float* __restrict__ sum,
                            const float* __restrict__ sq,
                            const float* __restrict__ gamma,
                            const float* __restrict__ beta,
                            const float* __restrict__ W,
                            const float* __restrict__ b,
                            unsigned short* __restrict__ Wh,
                            unsigned short* __restrict__ Wl,
                            float* __restrict__ bf, float invM) {
    int j = blockIdx.x;
    int k = threadIdx.x;
    float mean = sum[k] * invM;
    float var = sq[k] * invM - mean * mean;
    float scale = gamma[k] * rsqrtf(var + 1e-5f);
    float shift = beta[k] - mean * scale;
    float w = W[k * D + j];
    float wf = scale * w;
    unsigned int hi = bf16_rn(wf);
    size_t o = (size_t)((k >> 3) * 128 + j) * 8 + (k & 7);
    Wh[o] = (unsigned short)hi;
    Wl[o] = (unsigned short)bf16_rn(wf - bf16_f(hi));
    float v = shift * w;
#pragma unroll
    for (int of = 32; of; of >>= 1) v += __shfl_down(v, of);
    __shared__ float ws2[2];
    if ((k & 63) == 0) ws2[k >> 6] = v;
    __syncthreads();
    if (k == 0) bf[j] = b[j] + ws2[0] + ws2[1];
}

// ---------------------------------------------------------------------------
// Split-bf16 MFMA GEMM (layers 2,3), pre-split packed A, frag-major W.
// Block = 4 waves, BM = 128 (wave: 2 row-tiles x 8 col-tiles).
// ---------------------------------------------------------------------------
template <bool SILU, bool STATS, bool PACKOUT>
__global__ __launch_bounds__(256, 2) void gemm_mfma(
    const unsigned int* __restrict__ A0,
    const unsigned short* __restrict__ Wh,
    const unsigned short* __restrict__ Wl,
    const float* __restrict__ bias, unsigned int* __restrict__ Cp,
    float* __restrict__ Cf, float* __restrict__ gsum,
    float* __restrict__ gsq, int M) {
    const int tid = threadIdx.x;
    const int w = tid >> 6;
    const int l = tid & 63;
    const int lr = l & 15;
    const int lk = l >> 4;
    const int row0 = blockIdx.x * 128 + w * 32;

    facc acc[2][8];
#pragma unroll
    for (int rt = 0; rt < 2; ++rt)
#pragma unroll
        for (int ct = 0; ct < 8; ++ct)
#pragma unroll
            for (int r = 0; r < 4; ++r) acc[rt][ct][r] = 0.f;

    for (int s = 0; s < 4; ++s) {
        const int kb = s * 32 + lk * 8;
        bfrag ah[2], al[2];
#pragma unroll
        for (int rt = 0; rt < 2; ++rt) {
            const int arow = row0 + rt * 16 + lr;
            u32x4 q0 = {0u, 0u, 0u, 0u}, q1 = {0u, 0u, 0u, 0u};
            if (arow < M) {
                const u32x4* p = (const u32x4*)(A0 + (size_t)arow * D + kb);
                q0 = p[0];
                q1 = p[1];
            }
            unsigned int ua[8] = {q0.x, q0.y, q0.z, q0.w,
                                  q1.x, q1.y, q1.z, q1.w};
            u32x4 uh, ul;
#pragma unroll
            for (int r = 0; r < 4; ++r) {
                uh[r] = __builtin_amdgcn_perm(ua[2 * r + 1], ua[2 * r],
                                              0x07060302u);
                ul[r] = __builtin_amdgcn_perm(ua[2 * r + 1], ua[2 * r],
                                              0x05040100u);
            }
            ah[rt] = __builtin_bit_cast(bfrag, uh);
            al[rt] = __builtin_bit_cast(bfrag, ul);
        }
        bfrag bh[8], bl[8];
        const int fb = (s * 4 + lk) * 128;
#pragma unroll
        for (int ct = 0; ct < 8; ++ct) {
            size_t o = (size_t)(fb + ct * 16 + lr) * 8;
            bh[ct] = *(const bfrag*)(Wh + o);
            bl[ct] = *(const bfrag*)(Wl + o);
        }
#pragma unroll
        for (int rt = 0; rt < 2; ++rt)
#pragma unroll
            for (int ct = 0; ct < 8; ++ct)
                acc[rt][ct] = mfma16(ah[rt], bh[ct], acc[rt][ct]);
#pragma unroll
        for (int rt = 0; rt < 2; ++rt)
#pragma unroll
            for (int ct = 0; ct < 8; ++ct)
                acc[rt][ct] = mfma16(ah[rt], bl[ct], acc[rt][ct]);
#pragma unroll
        for (int rt = 0; rt < 2; ++rt)
#pragma unroll
            for (int ct = 0; ct < 8; ++ct)
                acc[rt][ct] = mfma16(al[rt], bh[ct], acc[rt][ct]);
    }

    __shared__ float sred[2][4][128];
#pragma unroll
    for (int ct = 0; ct < 8; ++ct) {
        const int col = ct * 16 + lr;
        const float bj = bias[col];
        float s = 0.f, q = 0.f;
#pragma unroll
        for (int rt = 0; rt < 2; ++rt) {
            const int base = row0 + rt * 16 + lk * 4;
#pragma unroll
            for (int r = 0; r < 4; ++r) {
                int crow = base + r;
                if (crow < M) {
                    float v = acc[rt][ct][r] + bj;
                    if (SILU) v = v / (1.0f + __expf(-v));
                    if (PACKOUT) Cp[(size_t)crow * D + col] = packf(v);
                    else         Cf[(size_t)crow * D + col] = v;
                    if (STATS) { s += v; q += v * v; }
                }
            }
        }
        if (STATS) {
            s += __shfl_xor(s, 16);
            s += __shfl_xor(s, 32);
            q += __shfl_xor(q, 16);
            q += __shfl_xor(q, 32);
            if (lk == 0) {
                sred[0][w][col] = s;
                sred[1][w][col] = q;
            }
        }
    }
    if (STATS) {
        __syncthreads();
        if (tid < 128) {
            float v = sred[0][0][tid] + sred[0][1][tid] + sred[0][2][tid] +
                      sred[0][3][tid];
            unsafeAtomicAdd(&gsum[tid], v);
        } else {
            int c = tid - 128;
            float v = sred[1][0][c] + sred[1][1][c] + sred[1][2][c] +
                      sred[1][3][c];
            unsafeAtomicAdd(&gsq[c], v);
        }
    }
}

extern "C" void kernel_launch(void* const* d_in, const int* in_sizes, int n_in,
                              void* d_out, int out_size, void* d_ws,
                              size_t ws_size, hipStream_t stream) {
    const float* x     = (const float*)d_in[0];
    const int*   eidx  = (const int*)d_in[1];
    const float* eattr = (const float*)d_in[2];
    const float* W1  = (const float*)d_in[3];
    const float* b1  = (const float*)d_in[4];
    const float* g1  = (const float*)d_in[5];
    const float* be1 = (const float*)d_in[6];
    const float* W2  = (const float*)d_in[7];
    const float* b2  = (const float*)d_in[8];
    const float* g2  = (const float*)d_in[9];
    const float* be2 = (const float*)d_in[10];
    const float* W3  = (const float*)d_in[11];
    const float* b3  = (const float*)d_in[12];

    const int M = in_sizes[0] / D;   // 50000
    const int E = in_sizes[1] / 2;   // 600000
    const int* srcIdx = eidx;

    unsigned int* wsu = (unsigned int*)d_ws;
    unsigned int* ebS = wsu;                        // E*64 uints (bf16 rows)
    unsigned int* xp  = ebS + (size_t)E * 64;       // M*D
    unsigned int* h1p = xp + (size_t)M * D;         // M*D
    unsigned int* h2p = h1p + (size_t)M * D;        // M*D
    float* sum1 = (float*)(h2p + (size_t)M * D);    // D
    float* sq1  = sum1 + D;
    float* sum2 = sq1 + D;
    float* sq2  = sum2 + D;
    float* b2f  = sq2 + D;
    float* b3f  = b2f + D;
    int* counts = (int*)(b3f + D);                  // M
    int* off    = counts + M;                       // M+4
    int* cur    = off + M + 4;                      // M
    int* bsum   = cur + M;                          // 64
    unsigned short* W1h = (unsigned short*)(bsum + 64);  // 128*256
    unsigned short* W1l = W1h + 256 * D;
    unsigned short* W2h = W1l + 256 * D;                 // 128*128
    unsigned short* W2l = W2h + D * D;
    unsigned short* W3h = W2l + D * D;
    unsigned short* W3l = W3h + D * D;

    float* out = (float*)d_out;

    (void)hipMemsetAsync(counts, 0, (size_t)M * sizeof(int), stream);
    (void)hipMemsetAsync(sum1, 0, 4 * D * sizeof(float), stream);

    const int eblk = (E + 255) / 256;
    const int sblk = (M * 32 + 255) / 256;
    prep_kernel<<<eblk + sblk + 128, 256, 0, stream>>>(
        srcIdx, counts, E, x, xp, M * 32, W1, W1h, W1l, eblk, sblk);

    const int nb = (M + SCHUNK - 1) / SCHUNK;   // 25
    scan1_kernel<<<nb, 256, 0, stream>>>(counts, bsum, M);
    scan2_kernel<<<1, 64, 0, stream>>>(bsum, nb);
    scan3_kernel<<<nb, 256, 0, stream>>>(counts, bsum, off, cur, M);

    fillp_kernel<<<(E + 7) / 8, 256, 0, stream>>>(eattr, srcIdx, cur, ebS, E);

    gemm1_fused<<<(M + 63) / 64, 256, 0, stream>>>(
        xp, ebS, off, W1h, W1l, b1, h1p, sum1, sq1, M);

    int nblk = (M + 127) / 128;
    fold_kernel<<<D, D, 0, stream>>>(sum1, sq1, g1, be1, W2, b2, W2h, W2l,
                                     b2f, 1.0f / (float)M);
    gemm_mfma<true, true, true><<<nblk, 256, 0, stream>>>(
        h1p, W2h, W2l, b2f, h2p, nullptr, sum2, sq2, M);
    fold_kernel<<<D, D, 0, stream>>>(sum2, sq2, g2, be2, W3, b3, W3h, W3l,
                                     b3f, 1.0f / (float)M);
    gemm_mfma<false, false, false><<<nblk, 256, 0, stream>>>(
        h2p, W3h, W3l, b3f, nullptr, out, nullptr, nullptr, M);
}

// Round 8
// 258.197 us; speedup vs baseline: 1.0827x; 1.0827x over previous
//
#include <hip/hip_runtime.h>
#include <hip/hip_bf16.h>

#define D 128

typedef __attribute__((ext_vector_type(8))) short bfrag;   // 8 bf16 (4 VGPRs)
typedef __attribute__((ext_vector_type(4))) float facc;    // 4 f32 acc
typedef __attribute__((ext_vector_type(4))) unsigned int u32x4;
typedef __attribute__((ext_vector_type(2))) unsigned int u32x2;
typedef __attribute__((ext_vector_type(4))) float f32x4;

__device__ __forceinline__ facc mfma16(bfrag a, bfrag b, facc c) {
    return __builtin_amdgcn_mfma_f32_16x16x32_bf16(a, b, c, 0, 0, 0);
}
__device__ __forceinline__ unsigned int bf16_rn(float f) {
    unsigned int u = __float_as_uint(f);
    u += 0x7FFF + ((u >> 16) & 1);   // round-nearest-even
    return u >> 16;
}
__device__ __forceinline__ float bf16_f(unsigned int h) {
    return __uint_as_float(h << 16);
}
// pack f32 -> (bf16_hi << 16) | bf16_lo
__device__ __forceinline__ unsigned int packf(float v) {
    unsigned int hi = bf16_rn(v);
    unsigned int lo = bf16_rn(v - bf16_f(hi));
    return (hi << 16) | lo;
}
__device__ __forceinline__ float bf16lo(unsigned int u) {
    return __uint_as_float(u << 16);
}
__device__ __forceinline__ float bf16hi(unsigned int u) {
    return __uint_as_float(u & 0xFFFF0000u);
}

// ---------------------------------------------------------------------------
// Fused prep: [0,eblk) histogram of src; [eblk,eblk+sblk) split x -> packed;
// [eblk+sblk, +128) W1 -> frag-major split-bf16 planes.
// ---------------------------------------------------------------------------
__global__ __launch_bounds__(256) void prep_kernel(
    const int* __restrict__ src, int* __restrict__ counts, int nedges,
    const float* __restrict__ x, unsigned int* __restrict__ xp, int n4,
    const float* __restrict__ W1, unsigned short* __restrict__ Wh,
    unsigned short* __restrict__ Wl, int eblk, int sblk) {
    int b = blockIdx.x;
    if (b < eblk) {
        int e = b * 256 + threadIdx.x;
        if (e < nedges) atomicAdd(&counts[src[e]], 1);
    } else if (b < eblk + sblk) {
        int i = (b - eblk) * 256 + threadIdx.x;
        if (i < n4) {
            float4 v = ((const float4*)x)[i];
            uint4 p;
            p.x = packf(v.x);
            p.y = packf(v.y);
            p.z = packf(v.z);
            p.w = packf(v.w);
            ((uint4*)xp)[i] = p;
        }
    } else {
        int j = b - eblk - sblk;   // 0..127 output col
        int k = threadIdx.x;       // 0..255
        float w = W1[(size_t)k * D + j];
        unsigned int hi = bf16_rn(w);
        size_t o = (size_t)((k >> 3) * 128 + j) * 8 + (k & 7);
        Wh[o] = (unsigned short)hi;
        Wl[o] = (unsigned short)bf16_rn(w - bf16_f(hi));
    }
}

// ---------------------------------------------------------------------------
// Multi-block exclusive scan of counts[n] (3 passes).
// ---------------------------------------------------------------------------
#define SCHUNK 2048
__global__ __launch_bounds__(256) void scan1_kernel(
    const int* __restrict__ counts, int* __restrict__ bsum, int n) {
    __shared__ int sd[256];
    const int tid = threadIdx.x;
    const int base = blockIdx.x * SCHUNK + tid * 8;
    int s = 0;
#pragma unroll
    for (int j = 0; j < 8; ++j) {
        int idx = base + j;
        if (idx < n) s += counts[idx];
    }
    sd[tid] = s;
    __syncthreads();
    for (int d2 = 128; d2; d2 >>= 1) {
        if (tid < d2) sd[tid] += sd[tid + d2];
        __syncthreads();
    }
    if (tid == 0) bsum[blockIdx.x] = sd[0];
}
__global__ void scan2_kernel(int* __restrict__ bsum, int nb) {
    int tid = threadIdx.x;
    int v = (tid < nb) ? bsum[tid] : 0;
#pragma unroll
    for (int d2 = 1; d2 < 64; d2 <<= 1) {
        int t = __shfl_up(v, d2);
        if (tid >= d2) v += t;
    }
    if (tid < nb) bsum[tid] = v;
}
__global__ __launch_bounds__(256) void scan3_kernel(
    const int* __restrict__ counts, const int* __restrict__ bsum,
    int* __restrict__ off, int* __restrict__ cur, int n) {
    __shared__ int sd[256];
    const int tid = threadIdx.x;
    const int base = blockIdx.x * SCHUNK + tid * 8;
    int loc[8];
    int s = 0;
#pragma unroll
    for (int j = 0; j < 8; ++j) {
        int idx = base + j;
        int c = (idx < n) ? counts[idx] : 0;
        loc[j] = c;
        s += c;
    }
    sd[tid] = s;
    __syncthreads();
#pragma unroll
    for (int d2 = 1; d2 < 256; d2 <<= 1) {
        int t = (tid >= d2) ? sd[tid - d2] : 0;
        __syncthreads();
        sd[tid] += t;
        __syncthreads();
    }
    int boff = (blockIdx.x == 0) ? 0 : bsum[blockIdx.x - 1];
    int pre = boff + sd[tid] - s;
#pragma unroll
    for (int j = 0; j < 8; ++j) {
        int idx = base + j;
        if (idx < n) {
            off[idx] = pre;
            cur[idx] = pre;
            pre += loc[j];
        }
    }
    if (tid == 255 && base + 8 >= n && n <= blockIdx.x * SCHUNK + SCHUNK)
        off[n] = boff + sd[255];
}

// ---------------------------------------------------------------------------
// Fill-permute: read edge rows SEQUENTIALLY (nontemporal), convert to bf16,
// write each row to its CSR-sorted slot (random 256B full-line writes,
// posted/L3-absorbed; 154MB sorted buffer < 256MB L3). Half-wave per row,
// 2 rows per half-wave for ILP.
// ---------------------------------------------------------------------------
__global__ __launch_bounds__(256) void fillp_kernel(
    const float* __restrict__ edge_attr, const int* __restrict__ src,
    int* __restrict__ cur, unsigned int* __restrict__ ebS, int nedges) {
    const int l = threadIdx.x & 63;
    const int h = l >> 5;           // half-wave
    const int c = l & 31;           // 4 cols per lane
    const int e0 = blockIdx.x * 16 + (threadIdx.x >> 6) * 2 + h;
#pragma unroll
    for (int rep = 0; rep < 2; ++rep) {
        int e = e0 + rep * 8;
        if (e >= nedges) continue;
        f32x4 v = __builtin_nontemporal_load(
            (const f32x4*)(edge_attr + (size_t)e * D) + c);
        int slot = 0;
        if (c == 0) slot = atomicAdd(&cur[src[e]], 1);
        slot = __shfl(slot, l & 32);    // broadcast from lane h*32
        u32x2 p;
        p.x = bf16_rn(v[0]) | (bf16_rn(v[1]) << 16);
        p.y = bf16_rn(v[2]) | (bf16_rn(v[3]) << 16);
        *((u32x2*)(ebS + (size_t)slot * 64) + c) = p;
    }
}

// ---------------------------------------------------------------------------
// Sequential gather: one WAVE per node. The node's sorted rows are
// contiguous; stream them (2 rows/instr via half-waves, 8 rows in flight),
// sum in f32, write packed split-bf16 agg row. 12500 blocks -> full machine.
// ---------------------------------------------------------------------------
__global__ __launch_bounds__(256) void gatherS_kernel(
    const unsigned int* __restrict__ ebS, const int* __restrict__ off,
    unsigned int* __restrict__ aggp, int nnodes) {
    int node = blockIdx.x * 4 + (threadIdx.x >> 6);
    int lane = threadIdx.x & 63;
    if (node >= nnodes) return;
    const int h = lane >> 5;
    const int c = lane & 31;
    int i = off[node];
    const int e = off[node + 1];
    f32x4 acc = {0.f, 0.f, 0.f, 0.f};
    for (; i + 8 <= e; i += 8) {
        u32x2 q[4];
#pragma unroll
        for (int u = 0; u < 4; ++u)
            q[u] = __builtin_nontemporal_load(
                (const u32x2*)(ebS + (size_t)(i + 2 * u + h) * 64) + c);
#pragma unroll
        for (int u = 0; u < 4; ++u) {
            acc[0] += bf16lo(q[u].x);
            acc[1] += bf16hi(q[u].x);
            acc[2] += bf16lo(q[u].y);
            acc[3] += bf16hi(q[u].y);
        }
    }
    for (; i + 2 <= e; i += 2) {
        u32x2 q = __builtin_nontemporal_load(
            (const u32x2*)(ebS + (size_t)(i + h) * 64) + c);
        acc[0] += bf16lo(q.x);
        acc[1] += bf16hi(q.x);
        acc[2] += bf16lo(q.y);
        acc[3] += bf16hi(q.y);
    }
    if (i < e && h == 0) {
        u32x2 q = __builtin_nontemporal_load(
            (const u32x2*)(ebS + (size_t)i * 64) + c);
        acc[0] += bf16lo(q.x);
        acc[1] += bf16hi(q.x);
        acc[2] += bf16lo(q.y);
        acc[3] += bf16hi(q.y);
    }
#pragma unroll
    for (int r = 0; r < 4; ++r) acc[r] += __shfl_xor(acc[r], 32);
    if (h == 0) {
        u32x4 p;
#pragma unroll
        for (int r = 0; r < 4; ++r) p[r] = packf(acc[r]);
        *((u32x4*)(aggp + (size_t)node * D) + c) = p;
    }
}

// ---------------------------------------------------------------------------
// Fold BN (batch stats) into next layer's W; frag-major split planes + bias.
// ---------------------------------------------------------------------------
__global__ void fold_kernel(const float* __restrict__ sum,
                            const float* __restrict__ sq,
                            const float* __restrict__ gamma,
                            const float* __restrict__ beta,
                            const float* __restrict__ W,
                            const float* __restrict__ b,
                            unsigned short* __restrict__ Wh,
                            unsigned short* __restrict__ Wl,
                            float* __restrict__ bf, float invM) {
    int j = blockIdx.x;
    int k = threadIdx.x;
    float mean = sum[k] * invM;
    float var = sq[k] * invM - mean * mean;
    float scale = gamma[k] * rsqrtf(var + 1e-5f);
    float shift = beta[k] - mean * scale;
    float w = W[k * D + j];
    float wf = scale * w;
    unsigned int hi = bf16_rn(wf);
    size_t o = (size_t)((k >> 3) * 128 + j) * 8 + (k & 7);
    Wh[o] = (unsigned short)hi;
    Wl[o] = (unsigned short)bf16_rn(wf - bf16_f(hi));
    float v = shift * w;
#pragma unroll
    for (int of = 32; of; of >>= 1) v += __shfl_down(v, of);
    __shared__ float ws2[2];
    if ((k & 63) == 0) ws2[k >> 6] = v;
    __syncthreads();
    if (k == 0) bf[j] = b[j] + ws2[0] + ws2[1];
}

// ---------------------------------------------------------------------------
// Split-bf16 MFMA GEMM, pre-split packed A (uint = hi|lo), frag-major W.
// 3 MFMAs per tile: Ah*Wh + Ah*Wl + Al*Wh. Block = 4 waves, BM = 128.
// K==256: k<128 from A0, k>=128 from A1 (implicit concat).
// C/D layout (m89): col = lane&15, row = (lane>>4)*4 + reg.
// ---------------------------------------------------------------------------
template <int K, bool SILU, bool STATS, bool PACKOUT>
__global__ __launch_bounds__(256, 2) void gemm_mfma(
    const unsigned int* __restrict__ A0, const unsigned int* __restrict__ A1,
    const unsigned short* __restrict__ Wh,
    const unsigned short* __restrict__ Wl,
    const float* __restrict__ bias, unsigned int* __restrict__ Cp,
    float* __restrict__ Cf, float* __restrict__ gsum,
    float* __restrict__ gsq, int M) {
    constexpr int NS = K / 32;
    const int tid = threadIdx.x;
    const int w = tid >> 6;
    const int l = tid & 63;
    const int lr = l & 15;
    const int lk = l >> 4;
    const int row0 = blockIdx.x * 128 + w * 32;

    facc acc[2][8];
#pragma unroll
    for (int rt = 0; rt < 2; ++rt)
#pragma unroll
        for (int ct = 0; ct < 8; ++ct)
#pragma unroll
            for (int r = 0; r < 4; ++r) acc[rt][ct][r] = 0.f;

    for (int s = 0; s < NS; ++s) {
        const int kb = s * 32 + lk * 8;
        bfrag ah[2], al[2];
#pragma unroll
        for (int rt = 0; rt < 2; ++rt) {
            const int arow = row0 + rt * 16 + lr;
            const unsigned int* As = A0;
            int kk = kb;
            if (K == 256 && s >= 4) { As = A1; kk = kb - 128; }
            u32x4 q0 = {0u, 0u, 0u, 0u}, q1 = {0u, 0u, 0u, 0u};
            if (arow < M) {
                const u32x4* p = (const u32x4*)(As + (size_t)arow * D + kk);
                q0 = p[0];
                q1 = p[1];
            }
            unsigned int ua[8] = {q0.x, q0.y, q0.z, q0.w,
                                  q1.x, q1.y, q1.z, q1.w};
            u32x4 uh, ul;
#pragma unroll
            for (int r = 0; r < 4; ++r) {
                uh[r] = __builtin_amdgcn_perm(ua[2 * r + 1], ua[2 * r],
                                              0x07060302u);
                ul[r] = __builtin_amdgcn_perm(ua[2 * r + 1], ua[2 * r],
                                              0x05040100u);
            }
            ah[rt] = __builtin_bit_cast(bfrag, uh);
            al[rt] = __builtin_bit_cast(bfrag, ul);
        }
        bfrag bh[8], bl[8];
        const int fb = (s * 4 + lk) * 128;
#pragma unroll
        for (int ct = 0; ct < 8; ++ct) {
            size_t o = (size_t)(fb + ct * 16 + lr) * 8;
            bh[ct] = *(const bfrag*)(Wh + o);
            bl[ct] = *(const bfrag*)(Wl + o);
        }
#pragma unroll
        for (int rt = 0; rt < 2; ++rt)
#pragma unroll
            for (int ct = 0; ct < 8; ++ct)
                acc[rt][ct] = mfma16(ah[rt], bh[ct], acc[rt][ct]);
#pragma unroll
        for (int rt = 0; rt < 2; ++rt)
#pragma unroll
            for (int ct = 0; ct < 8; ++ct)
                acc[rt][ct] = mfma16(ah[rt], bl[ct], acc[rt][ct]);
#pragma unroll
        for (int rt = 0; rt < 2; ++rt)
#pragma unroll
            for (int ct = 0; ct < 8; ++ct)
                acc[rt][ct] = mfma16(al[rt], bh[ct], acc[rt][ct]);
    }

    __shared__ float sred[2][4][128];
#pragma unroll
    for (int ct = 0; ct < 8; ++ct) {
        const int col = ct * 16 + lr;
        const float bj = bias[col];
        float s = 0.f, q = 0.f;
#pragma unroll
        for (int rt = 0; rt < 2; ++rt) {
            const int base = row0 + rt * 16 + lk * 4;
#pragma unroll
            for (int r = 0; r < 4; ++r) {
                int crow = base + r;
                if (crow < M) {
                    float v = acc[rt][ct][r] + bj;
                    if (SILU) v = v / (1.0f + __expf(-v));
                    if (PACKOUT) Cp[(size_t)crow * D + col] = packf(v);
                    else         Cf[(size_t)crow * D + col] = v;
                    if (STATS) { s += v; q += v * v; }
                }
            }
        }
        if (STATS) {
            s += __shfl_xor(s, 16);
            s += __shfl_xor(s, 32);
            q += __shfl_xor(q, 16);
            q += __shfl_xor(q, 32);
            if (lk == 0) {
                sred[0][w][col] = s;
                sred[1][w][col] = q;
            }
        }
    }
    if (STATS) {
        __syncthreads();
        if (tid < 128) {
            float v = sred[0][0][tid] + sred[0][1][tid] + sred[0][2][tid] +
                      sred[0][3][tid];
            unsafeAtomicAdd(&gsum[tid], v);
        } else {
            int c = tid - 128;
            float v = sred[1][0][c] + sred[1][1][c] + sred[1][2][c] +
                      sred[1][3][c];
            unsafeAtomicAdd(&gsq[c], v);
        }
    }
}

extern "C" void kernel_launch(void* const* d_in, const int* in_sizes, int n_in,
                              void* d_out, int out_size, void* d_ws,
                              size_t ws_size, hipStream_t stream) {
    const float* x     = (const float*)d_in[0];
    const int*   eidx  = (const int*)d_in[1];
    const float* eattr = (const float*)d_in[2];
    const float* W1  = (const float*)d_in[3];
    const float* b1  = (const float*)d_in[4];
    const float* g1  = (const float*)d_in[5];
    const float* be1 = (const float*)d_in[6];
    const float* W2  = (const float*)d_in[7];
    const float* b2  = (const float*)d_in[8];
    const float* g2  = (const float*)d_in[9];
    const float* be2 = (const float*)d_in[10];
    const float* W3  = (const float*)d_in[11];
    const float* b3  = (const float*)d_in[12];

    const int M = in_sizes[0] / D;   // 50000
    const int E = in_sizes[1] / 2;   // 600000
    const int* srcIdx = eidx;

    unsigned int* wsu = (unsigned int*)d_ws;
    unsigned int* ebS = wsu;                        // E*64 uints (bf16 rows)
    unsigned int* xp  = ebS + (size_t)E * 64;       // M*D
    unsigned int* h1p = xp + (size_t)M * D;         // M*D
    unsigned int* h2p = h1p + (size_t)M * D;        // M*D (also aliased: agg)
    float* sum1 = (float*)(h2p + (size_t)M * D);    // D
    float* sq1  = sum1 + D;
    float* sum2 = sq1 + D;
    float* sq2  = sum2 + D;
    float* b2f  = sq2 + D;
    float* b3f  = b2f + D;
    int* counts = (int*)(b3f + D);                  // M
    int* off    = counts + M;                       // M+4
    int* cur    = off + M + 4;                      // M
    int* bsum   = cur + M;                          // 64
    unsigned short* W1h = (unsigned short*)(bsum + 64);  // 128*256
    unsigned short* W1l = W1h + 256 * D;
    unsigned short* W2h = W1l + 256 * D;                 // 128*128
    unsigned short* W2l = W2h + D * D;
    unsigned short* W3h = W2l + D * D;
    unsigned short* W3l = W3h + D * D;

    // agg aliases h2p: gatherS writes it, gemm1 (only consumer) reads it,
    // then gemm2 overwrites h2p. No overlap in live ranges.
    unsigned int* aggp = h2p;

    float* out = (float*)d_out;

    (void)hipMemsetAsync(counts, 0, (size_t)M * sizeof(int), stream);
    (void)hipMemsetAsync(sum1, 0, 4 * D * sizeof(float), stream);

    const int eblk = (E + 255) / 256;
    const int sblk = (M * 32 + 255) / 256;
    prep_kernel<<<eblk + sblk + 128, 256, 0, stream>>>(
        srcIdx, counts, E, x, xp, M * 32, W1, W1h, W1l, eblk, sblk);

    const int nb = (M + SCHUNK - 1) / SCHUNK;   // 25
    scan1_kernel<<<nb, 256, 0, stream>>>(counts, bsum, M);
    scan2_kernel<<<1, 64, 0, stream>>>(bsum, nb);
    scan3_kernel<<<nb, 256, 0, stream>>>(counts, bsum, off, cur, M);

    fillp_kernel<<<(E + 15) / 16, 256, 0, stream>>>(eattr, srcIdx, cur, ebS, E);

    gatherS_kernel<<<(M + 3) / 4, 256, 0, stream>>>(ebS, off, aggp, M);

    int nblk = (M + 127) / 128;
    gemm_mfma<256, true, true, true><<<nblk, 256, 0, stream>>>(
        xp, aggp, W1h, W1l, b1, h1p, nullptr, sum1, sq1, M);
    fold_kernel<<<D, D, 0, stream>>>(sum1, sq1, g1, be1, W2, b2, W2h, W2l,
                                     b2f, 1.0f / (float)M);
    gemm_mfma<128, true, true, true><<<nblk, 256, 0, stream>>>(
        h1p, nullptr, W2h, W2l, b2f, h2p, nullptr, sum2, sq2, M);
    fold_kernel<<<D, D, 0, stream>>>(sum2, sq2, g2, be2, W3, b3, W3h, W3l,
                                     b3f, 1.0f / (float)M);
    gemm_mfma<128, false, false, false><<<nblk, 256, 0, stream>>>(
        h2p, nullptr, W3h, W3l, b3f, nullptr, out, nullptr, nullptr, M);
}